// Round 1
// baseline (305.771 us; speedup 1.0000x reference)
//
#include <hip/hip_runtime.h>

// Problem constants (from reference): B=256, x:[B,80,14,14], w1:[512,80], b1:[512],
// w2:[512,512], b2:[512], w3:[512,4,14,14], fc_w:[80,2048], fc_b:[80], out:[B,80].
#define CIN 80      // input channels
#define NSP 196     // 14*14 spatial
#define XST 208     // x LDS row stride (zero-padded 196->208 so 16x13 thread tiling is safe)
#define WST 68      // W LDS row stride (mult of 4 => 16B-aligned b128 reads, bank-safe)
#define GCH 64      // groups per block

// k1: compose W = w2@w1 [512x80], biasc = w2@b1 + b2 [512]; init out = fc_b broadcast.
// Cost: 512 blocks x 80 lanes x 512 MAC ~ trivial.
__global__ __launch_bounds__(128) void k1_compose(
    const float* __restrict__ w1, const float* __restrict__ b1,
    const float* __restrict__ w2, const float* __restrict__ b2,
    const float* __restrict__ fc_b,
    float* __restrict__ Wc, float* __restrict__ biasc,
    float* __restrict__ out, int out_total)
{
    const int o = blockIdx.x;
    const int t = threadIdx.x;
    const float* __restrict__ w2row = w2 + (size_t)o * 512;
    if (t < CIN) {
        float acc = 0.f;
        #pragma unroll 4
        for (int c = 0; c < 512; ++c)
            acc = fmaf(w2row[c], w1[c * CIN + t], acc);   // w1 coalesced over lanes
        Wc[o * CIN + t] = acc;
    } else if (t == CIN) {
        float acc = b2[o];
        for (int c = 0; c < 512; ++c)
            acc = fmaf(w2row[c], b1[c], acc);
        biasc[o] = acc;
    }
    // init out with fc bias (atomicAdd target in k2). 512*128 = 65536 >= out_total.
    const int idx = blockIdx.x * 128 + t;
    if (idx < out_total) out[idx] = fc_b[idx % CIN];
}

// k2: per block = (batch b, 64-group chunk). Fused:
//   h2[g][hw] = biasc[g] + sum_i W[g][i]*x[b][i][hw]   (register tile 4g x 13hw/thread)
//   g[b][g][o] = sum_hw h2*w3  (shfl reduce over tx)  -> relu -> LDS gl[256]
//   out[b][l] += sum_k gl[k]*fc_w[l][g0*4+k]           (atomicAdd)
__global__ __launch_bounds__(256) void k2_fused(
    const float* __restrict__ x, const float* __restrict__ w3,
    const float* __restrict__ fc_w,
    const float* __restrict__ Wc, const float* __restrict__ biasc,
    float* __restrict__ out)
{
    __shared__ float xs[40 * XST];   // 33.3 KB: half of x[b], zero-padded rows
    __shared__ float wt[CIN * WST];  // 21.8 KB: W chunk transposed wt[i][g]
    __shared__ float gl[GCH * 4];    // relu'd group outputs for this chunk
    __shared__ float bcs[GCH];

    const int t  = threadIdx.x;
    const int b  = blockIdx.x;           // fast grid dim: 8 gchunks of b share an XCD's L2
    const int g0 = blockIdx.y * GCH;
    const int tx = t & 15;               // 16 hw-lanes
    const int ty = t >> 4;               // 16 group-lanes (4 groups each)

    // stage W chunk transposed: wt[i*WST+g] = Wc[(g0+g)*80+i]
    for (int idx = t; idx < GCH * CIN; idx += 256) {
        const int g = idx / CIN, i = idx - g * CIN;
        wt[i * WST + g] = Wc[(g0 + g) * CIN + i];
    }
    if (t < GCH) bcs[t] = biasc[g0 + t];
    __syncthreads();

    float acc[4][13];
    #pragma unroll
    for (int gg = 0; gg < 4; ++gg) {
        const float bv = bcs[ty * 4 + gg];
        #pragma unroll
        for (int j = 0; j < 13; ++j) acc[gg][j] = bv;
    }

    const int hwbase = tx * 13;          // 13*tx mod 32 is a permutation -> no bank conflicts
    const float* __restrict__ xb = x + (size_t)b * (CIN * NSP);

    // GEMM over i in two 40-row halves to keep LDS under 64 KB
    for (int half = 0; half < 2; ++half) {
        const float* __restrict__ xh = xb + half * 40 * NSP;
        for (int idx = t; idx < 40 * XST; idx += 256) {
            const int i = idx / XST, c = idx - i * XST;
            xs[idx] = (c < NSP) ? xh[i * NSP + c] : 0.f;   // zero-pad cols 196..207
        }
        __syncthreads();
        const int ibase = half * 40;
        for (int i = 0; i < 40; ++i) {
            const float* __restrict__ xr = xs + i * XST + hwbase;
            const float* __restrict__ wr = wt + (ibase + i) * WST + ty * 4;  // 16B aligned
            const float w0 = wr[0], w1v = wr[1], w2v = wr[2], w3v = wr[3];
            #pragma unroll
            for (int j = 0; j < 13; ++j) {
                const float xv = xr[j];
                acc[0][j] = fmaf(w0,  xv, acc[0][j]);
                acc[1][j] = fmaf(w1v, xv, acc[1][j]);
                acc[2][j] = fmaf(w2v, xv, acc[2][j]);
                acc[3][j] = fmaf(w3v, xv, acc[3][j]);
            }
        }
        __syncthreads();
    }

    // conv3: partial dot over this thread's hw slice, reduce across the 16 tx lanes,
    // then relu (AFTER full spatial sum) into gl.
    #pragma unroll
    for (int gg = 0; gg < 4; ++gg) {
        const int g = g0 + ty * 4 + gg;
        const float* __restrict__ w3g = w3 + (size_t)g * (4 * NSP);
        #pragma unroll
        for (int o = 0; o < 4; ++o) {
            const float* __restrict__ w3r = w3g + o * NSP + hwbase;
            float p = 0.f;
            #pragma unroll
            for (int j = 0; j < 13; ++j) {
                const float wv = (hwbase + j < NSP) ? w3r[j] : 0.f;  // guard OOB (tx=15)
                p = fmaf(acc[gg][j], wv, p);
            }
            p += __shfl_down(p, 8, 16);
            p += __shfl_down(p, 4, 16);
            p += __shfl_down(p, 2, 16);
            p += __shfl_down(p, 1, 16);
            if (tx == 0) gl[(ty * 4 + gg) * 4 + o] = fmaxf(p, 0.f);
        }
    }
    __syncthreads();

    // fc partial for this chunk's 256 k-columns: 160 threads = 80 l x 2 k-halves.
    if (t < 160) {
        const int part = t / 80;
        const int l = t - part * 80;
        const float* __restrict__ fr = fc_w + (size_t)l * 2048 + g0 * 4 + part * 128;
        const float* __restrict__ gr = gl + part * 128;
        float s = 0.f;
        #pragma unroll 8
        for (int k = 0; k < 128; ++k) s = fmaf(gr[k], fr[k], s);
        atomicAdd(out + b * CIN + l, s);   // out pre-set to fc_b by k1
    }
}

extern "C" void kernel_launch(void* const* d_in, const int* in_sizes, int n_in,
                              void* d_out, int out_size, void* d_ws, size_t ws_size,
                              hipStream_t stream) {
    const float* x    = (const float*)d_in[0];
    const float* w1   = (const float*)d_in[1];
    const float* b1   = (const float*)d_in[2];
    const float* w2   = (const float*)d_in[3];
    const float* b2   = (const float*)d_in[4];
    const float* w3   = (const float*)d_in[5];
    const float* fc_w = (const float*)d_in[6];
    const float* fc_b = (const float*)d_in[7];
    float* out = (float*)d_out;

    float* Wc    = (float*)d_ws;          // 512*80 floats
    float* biasc = Wc + 512 * CIN;        // 512 floats

    const int B = in_sizes[0] / (CIN * NSP);   // 256

    k1_compose<<<512, 128, 0, stream>>>(w1, b1, w2, b2, fc_b, Wc, biasc, out, out_size);
    k2_fused<<<dim3(B, 512 / GCH), 256, 0, stream>>>(x, w3, fc_w, Wc, biasc, out);
}

// Round 2
// 175.589 us; speedup vs baseline: 1.7414x; 1.7414x over previous
//
#include <hip/hip_runtime.h>
#include <hip/hip_bf16.h>

// B=256, x:[B,80,14,14] f32, w1:[512,80], b1:[512], w2:[512,512], b2:[512],
// w3:[512,4,14,14], fc_w:[80,2048], fc_b:[80] -> out:[B,80] f32.
// Algebra: conv1+conv2 compose: h2 = (w2@w1) x + (w2@b1+b2). GEMM in bf16 MFMA.
#define CIN 80
#define NSP 196
#define KP  96          // K padded 80->96 (zeros), row stride (bf16) = 192 B (16B mult)
#define HWP 208         // hw padded 196->208 for w3t (13 n-tiles of 16)

typedef __attribute__((ext_vector_type(8))) short  short8;   // 8 bf16 = 1 MFMA A/B frag
typedef __attribute__((ext_vector_type(4))) float  floatx4;  // MFMA C/D frag

// ---------------- k1: W = w2@w1 (bf16), biasc = w2@b1+b2 (f32), out = fc_b ----
__global__ __launch_bounds__(128) void k1_compose(
    const float* __restrict__ w1, const float* __restrict__ b1,
    const float* __restrict__ w2, const float* __restrict__ b2,
    const float* __restrict__ fc_b,
    __hip_bfloat16* __restrict__ Wcbf, float* __restrict__ biasc,
    float* __restrict__ out, int out_total)
{
    const int o = blockIdx.x, t = threadIdx.x;
    const float* __restrict__ w2row = w2 + (size_t)o * 512;
    if (t < CIN) {
        float acc = 0.f;
        #pragma unroll 4
        for (int c = 0; c < 512; ++c) acc = fmaf(w2row[c], w1[c * CIN + t], acc);
        Wcbf[o * CIN + t] = __float2bfloat16(acc);
    } else if (t == CIN) {
        float acc = b2[o];
        for (int c = 0; c < 512; ++c) acc = fmaf(w2row[c], b1[c], acc);
        biasc[o] = acc;
    }
    const int idx = blockIdx.x * 128 + t;
    if (idx < out_total) out[idx] = fc_b[idx % CIN];
}

// ---------------- k0: x [b][k=80][hw=196] f32 -> xbf [b][hw=196][k=80] bf16 ---
__global__ __launch_bounds__(256) void k0_xpose(
    const float* __restrict__ x, __hip_bfloat16* __restrict__ xbf)
{
    __shared__ float tile[CIN * 197];   // stride 197: transposed reads conflict-free
    const int b = blockIdx.x, t = threadIdx.x;
    const float* __restrict__ xb = x + (size_t)b * (CIN * NSP);
    for (int idx = t; idx < CIN * NSP; idx += 256) {
        const int k = idx / NSP, hw = idx - k * NSP;
        tile[k * 197 + hw] = xb[idx];          // coalesced global, bank-stride-1 LDS
    }
    __syncthreads();
    __hip_bfloat16* __restrict__ ob = xbf + (size_t)b * (NSP * CIN);
    for (int idx = t; idx < NSP * CIN; idx += 256) {
        const int hw = idx / CIN, k = idx - hw * CIN;
        ob[idx] = __float2bfloat16(tile[k * 197 + hw]);  // stride-197 read: gcd(5,32)=1
    }
}

// ---------------- k3: w3 [g][o=4][hw=196] -> w3t [g][hw=208][o=4] f32, zero-pad
__global__ __launch_bounds__(256) void k3_w3t(
    const float* __restrict__ w3, float* __restrict__ w3t)
{
    const int g = blockIdx.x, t = threadIdx.x;
    if (t < HWP) {
        floatx4 v;
        #pragma unroll
        for (int o = 0; o < 4; ++o)
            v[o] = (t < NSP) ? w3[(size_t)g * (4 * NSP) + o * NSP + t] : 0.f;
        *(floatx4*)(w3t + ((size_t)g * HWP + t) * 4) = v;
    }
}

// ---------------- k2: fused MFMA GEMM + conv3 + relu + fc ---------------------
// block = (batch b, 128-group chunk gc). 4 waves; wave w owns groups [32w,32w+32).
__global__ __launch_bounds__(256, 2) void k2_mfma(
    const __hip_bfloat16* __restrict__ xbf, const __hip_bfloat16* __restrict__ Wcbf,
    const float* __restrict__ biasc, const float* __restrict__ w3t,
    const float* __restrict__ fc_w, float* __restrict__ out)
{
    __shared__ __align__(16) unsigned short xs[NSP * KP]; // 37632 B, rows k-contig
    __shared__ __align__(16) unsigned short wa[128 * KP]; // 24576 B
    __shared__ float gl[512];                             // relu'd group outputs
    __shared__ float bias_s[128];                         // total 64768 B < 64 KiB

    const int t = threadIdx.x;
    const int b = blockIdx.x, gc = blockIdx.y;

    // stage xs: 196 rows x 12 uint4-chunks (10 data + 2 zero pad to K=96)
    const uint4 z4 = {0u, 0u, 0u, 0u};
    const uint4* __restrict__ xsrc = (const uint4*)(xbf + (size_t)b * (NSP * CIN));
    uint4* xdst = (uint4*)xs;
    for (int idx = t; idx < NSP * 12; idx += 256) {
        const int r = idx / 12, c = idx - r * 12;
        xdst[idx] = (c < 10) ? xsrc[r * 10 + c] : z4;
    }
    // stage wa: 128 rows of W chunk, same padding
    const uint4* __restrict__ wsrc = (const uint4*)(Wcbf + (size_t)gc * 128 * CIN);
    uint4* wdst = (uint4*)wa;
    for (int idx = t; idx < 128 * 12; idx += 256) {
        const int r = idx / 12, c = idx - r * 12;
        wdst[idx] = (c < 10) ? wsrc[r * 10 + c] : z4;
    }
    if (t < 128) bias_s[t] = biasc[gc * 128 + t];
    __syncthreads();

    const int wave = t >> 6, lane = t & 63;
    const int col = lane & 15, quad = lane >> 4;
    const int gbl = wave * 32;                     // local group base of this wave

    floatx4 acc[2][13];
    #pragma unroll
    for (int mt = 0; mt < 2; ++mt)
        #pragma unroll
        for (int n = 0; n < 13; ++n) acc[mt][n] = 0.f;

    // frag base pointers: A[m=col][k=quad*8+j], B[n=col][k=quad*8+j] (k-contig rows)
    const unsigned short* __restrict__ wr0 = wa + (gbl + col) * KP + quad * 8;
    const unsigned short* __restrict__ wr1 = wa + (gbl + 16 + col) * KP + quad * 8;
    const unsigned short* __restrict__ xr  = xs + col * KP + quad * 8;

    #pragma unroll
    for (int ks = 0; ks < 3; ++ks) {               // K = 96 = 3 x 32 (last 16 zeros)
        const int k0 = ks * 32;
        const short8 a0 = *(const short8*)(wr0 + k0);
        const short8 a1 = *(const short8*)(wr1 + k0);
        #pragma unroll
        for (int n = 0; n < 13; ++n) {
            const short8 bf = *(const short8*)(xr + n * 16 * KP + k0);
            acc[0][n] = __builtin_amdgcn_mfma_f32_16x16x32_bf16(a0, bf, acc[0][n], 0, 0, 0);
            acc[1][n] = __builtin_amdgcn_mfma_f32_16x16x32_bf16(a1, bf, acc[1][n], 0, 0, 0);
        }
    }

    // bias add: C/D layout row(g) = quad*4 + r, col(hw) = lane&15  [m89-verified]
    #pragma unroll
    for (int mt = 0; mt < 2; ++mt)
        #pragma unroll
        for (int r = 0; r < 4; ++r) {
            const float bv = bias_s[gbl + mt * 16 + quad * 4 + r];
            #pragma unroll
            for (int n = 0; n < 13; ++n) acc[mt][n][r] += bv;
        }

    // conv3: outg[g][o] = sum_hw h2[g][hw]*w3[g][o][hw]; w3t gives float4 over o.
    // n=12 cols>=4 hold LDS garbage (possibly NaN) -> force 0 before reduce.
    #pragma unroll
    for (int mt = 0; mt < 2; ++mt)
        #pragma unroll
        for (int r = 0; r < 4; ++r) {
            const int g = gc * 128 + gbl + mt * 16 + quad * 4 + r;
            const float* __restrict__ wp = w3t + (size_t)g * (HWP * 4) + col * 4;
            float p0 = 0.f, p1 = 0.f, p2 = 0.f, p3 = 0.f;
            #pragma unroll
            for (int n = 0; n < 13; ++n) {
                float a = acc[mt][n][r];
                if (n == 12) a = (col < 4) ? a : 0.f;   // kill garbage lanes
                const floatx4 wv = *(const floatx4*)(wp + n * 64);
                p0 = fmaf(a, wv[0], p0);
                p1 = fmaf(a, wv[1], p1);
                p2 = fmaf(a, wv[2], p2);
                p3 = fmaf(a, wv[3], p3);
            }
            #pragma unroll
            for (int s = 8; s >= 1; s >>= 1) {       // reduce over 16 hw-lanes
                p0 += __shfl_down(p0, s, 16);
                p1 += __shfl_down(p1, s, 16);
                p2 += __shfl_down(p2, s, 16);
                p3 += __shfl_down(p3, s, 16);
            }
            if (col == 0) {
                const int gi = (gbl + mt * 16 + quad * 4 + r) * 4;
                gl[gi + 0] = fmaxf(p0, 0.f);
                gl[gi + 1] = fmaxf(p1, 0.f);
                gl[gi + 2] = fmaxf(p2, 0.f);
                gl[gi + 3] = fmaxf(p3, 0.f);
            }
        }
    __syncthreads();

    // fc partial over this chunk's 512 k-columns: 160 threads = 80 l x 2 halves
    if (t < 160) {
        const int part = t / 80, l = t - part * 80;
        const float* __restrict__ fr = fc_w + (size_t)l * 2048 + gc * 512 + part * 256;
        const float* __restrict__ gr = gl + part * 256;
        float s = 0.f;
        #pragma unroll 8
        for (int k = 0; k < 256; ++k) s = fmaf(gr[k], fr[k], s);
        atomicAdd(out + b * CIN + l, s);             // out pre-set to fc_b by k1
    }
}

extern "C" void kernel_launch(void* const* d_in, const int* in_sizes, int n_in,
                              void* d_out, int out_size, void* d_ws, size_t ws_size,
                              hipStream_t stream) {
    const float* x    = (const float*)d_in[0];
    const float* w1   = (const float*)d_in[1];
    const float* b1   = (const float*)d_in[2];
    const float* w2   = (const float*)d_in[3];
    const float* b2   = (const float*)d_in[4];
    const float* w3   = (const float*)d_in[5];
    const float* fc_w = (const float*)d_in[6];
    const float* fc_b = (const float*)d_in[7];
    float* out = (float*)d_out;

    const int B = in_sizes[0] / (CIN * NSP);   // 256

    // workspace layout (16B-aligned chunks): xbf | Wcbf | biasc | w3t  (~9.8 MB)
    char* ws = (char*)d_ws;
    __hip_bfloat16* xbf  = (__hip_bfloat16*)ws;                         // B*196*80*2
    size_t off = (size_t)B * NSP * CIN * 2;
    __hip_bfloat16* Wcbf = (__hip_bfloat16*)(ws + off);  off += 512 * CIN * 2;
    float* biasc         = (float*)(ws + off);           off += 512 * 4;
    float* w3t           = (float*)(ws + off);           // 512*208*4*4

    k1_compose<<<512, 128, 0, stream>>>(w1, b1, w2, b2, fc_b, Wcbf, biasc, out, out_size);
    k3_w3t<<<512, 256, 0, stream>>>(w3, w3t);
    k0_xpose<<<B, 256, 0, stream>>>(x, xbf);
    k2_mfma<<<dim3(B, 4), 256, 0, stream>>>(xbf, Wcbf, biasc, w3t, fc_w, out);
}

// Round 3
// 171.291 us; speedup vs baseline: 1.7851x; 1.0251x over previous
//
#include <hip/hip_runtime.h>
#include <hip/hip_bf16.h>

// B=256, x:[B,80,14,14] f32, w1:[512,80], b1:[512], w2:[512,512], b2:[512],
// w3:[512,4,14,14], fc_w:[80,2048], fc_b:[80] -> out:[B,80] f32.
// h2 = (w2@w1) x + (w2@b1+b2); bias folded in as k-channel 80 (x col = 1.0).
#define CIN 80
#define NSP 196
#define HWP 208        // hw padded 196->208 (13 n-tiles of 16)
#define KP  96         // k padded 80(+1 bias)->96 (3 MFMA k-steps of 32)
#define NB_WC 256      // 32 o-tiles x 8 k-chunks
#define NB_W3 512
#define NB_FT 512      // 512*320 = 163840 = 2048*80

typedef __attribute__((ext_vector_type(8))) short  short8;
typedef __attribute__((ext_vector_type(4))) float  floatx4;

static __device__ __forceinline__ unsigned short bf16(float f) {
    __hip_bfloat16 h = __float2bfloat16(f);
    return *(unsigned short*)&h;
}

// ---- kPre: multi-role prep (all roles independent) --------------------------
// roles by blockIdx.x: [0,256) Wc-partial | [256,256+4B) x-prep | w3-prep | fct
__global__ __launch_bounds__(320) void kPre(
    const float* __restrict__ x, const float* __restrict__ w1,
    const float* __restrict__ w2, const float* __restrict__ w3,
    const float* __restrict__ fc_w,
    float* __restrict__ Wcf, unsigned short* __restrict__ xbf,
    float* __restrict__ w3t, float* __restrict__ fct, int nb_xp)
{
    __shared__ float sm[6144];   // 24 KB union
    const int blk = blockIdx.x, t = threadIdx.x;

    if (blk < NB_WC) {
        // Wc[o][c] partial over 64-m chunk: stage w1 slab + w2 slab in LDS.
        const int ot = blk >> 3, kc = blk & 7;
        float* w1s = sm;          // [64][80]
        float* w2s = sm + 5120;   // [16][64]
        for (int idx = t; idx < 64 * 80; idx += 320) {
            const int m = idx / 80, c = idx - m * 80;
            w1s[idx] = w1[(kc * 64 + m) * CIN + c];
        }
        for (int idx = t; idx < 16 * 64; idx += 320) {
            const int o = idx >> 6, m = idx & 63;
            w2s[idx] = w2[(size_t)(ot * 16 + o) * 512 + kc * 64 + m];
        }
        __syncthreads();
        const int c = t % 80, oq = t / 80;          // oq 0..3
        float a0 = 0.f, a1 = 0.f, a2 = 0.f, a3 = 0.f;
        #pragma unroll 8
        for (int m = 0; m < 64; ++m) {
            const float xv = w1s[m * 80 + c];
            a0 = fmaf(w2s[(oq     ) * 64 + m], xv, a0);
            a1 = fmaf(w2s[(oq +  4) * 64 + m], xv, a1);
            a2 = fmaf(w2s[(oq +  8) * 64 + m], xv, a2);
            a3 = fmaf(w2s[(oq + 12) * 64 + m], xv, a3);
        }
        atomicAdd(Wcf + (ot * 16 + oq     ) * CIN + c, a0);
        atomicAdd(Wcf + (ot * 16 + oq +  4) * CIN + c, a1);
        atomicAdd(Wcf + (ot * 16 + oq +  8) * CIN + c, a2);
        atomicAdd(Wcf + (ot * 16 + oq + 12) * CIN + c, a3);
    } else if (blk < NB_WC + nb_xp) {
        // x [b][80][196] f32 -> xbf [b][208][96] bf16 (col80=1, pads=0)
        const int r = blk - NB_WC;
        const int b = r >> 2, ht = r & 3;
        const int hw0 = ht * 52;
        float* tile = sm;    // [80][53]: write hw-contig, read k-strided gcd(21,32)=1
        for (int idx = t; idx < 80 * 52; idx += 320) {
            const int k = idx / 52, hl = idx - k * 52;
            const int hw = hw0 + hl;
            tile[k * 53 + hl] = (hw < NSP) ? x[(size_t)b * CIN * NSP + k * NSP + hw] : 0.f;
        }
        __syncthreads();
        unsigned short* __restrict__ ob = xbf + (size_t)b * HWP * KP;
        for (int idx = t; idx < 52 * KP; idx += 320) {
            const int hl = idx / KP, k = idx - hl * KP;
            const int hw = hw0 + hl;
            float f = 0.f;
            if (hw < NSP) {
                if (k < CIN) f = tile[k * 53 + hl];
                else if (k == CIN) f = 1.f;         // bias channel
            }
            ob[hw * KP + k] = bf16(f);
        }
    } else if (blk < NB_WC + nb_xp + NB_W3) {
        // w3 [g][4][196] -> w3t [g][208][4] f32, zero-padded hw
        const int g = blk - NB_WC - nb_xp;
        if (t < HWP) {
            floatx4 v;
            #pragma unroll
            for (int o = 0; o < 4; ++o)
                v[o] = (t < NSP) ? w3[(size_t)g * (4 * NSP) + o * NSP + t] : 0.f;
            *(floatx4*)(w3t + ((size_t)g * HWP + t) * 4) = v;
        }
    } else {
        // fc_w [80][2048] -> fct [2048][80] (coalesced fc reads)
        const int idx = (blk - NB_WC - nb_xp - NB_W3) * 320 + t;  // < 163840
        const int k = idx / 80, l = idx - k * 80;
        fct[idx] = fc_w[(size_t)l * 2048 + k];
    }
}

// ---- kP2: finalize Wcbf [512][96] bf16 (col80=bias), init out=fc_b ----------
__global__ __launch_bounds__(128) void kP2(
    const float* __restrict__ w2, const float* __restrict__ b1,
    const float* __restrict__ b2, const float* __restrict__ fc_b,
    const float* __restrict__ Wcf, unsigned short* __restrict__ Wcbf,
    float* __restrict__ out, int out_total)
{
    __shared__ float red[128];
    const int o = blockIdx.x, t = threadIdx.x;
    float s = 0.f;
    for (int m = t; m < 512; m += 128) s = fmaf(w2[(size_t)o * 512 + m], b1[m], s);
    red[t] = s;
    __syncthreads();
    for (int st = 64; st > 0; st >>= 1) {
        if (t < st) red[t] += red[t + st];
        __syncthreads();
    }
    const float bias = red[0] + b2[o];
    if (t < KP) {
        const float f = (t < CIN) ? Wcf[o * CIN + t] : ((t == CIN) ? bias : 0.f);
        Wcbf[o * KP + t] = bf16(f);
    }
    const int idx = o * 128 + t;
    if (idx < out_total) out[idx] = fc_b[idx % CIN];
}

// ---- kM: main fused GEMM + conv3 + relu -> gbuf [B][2048] -------------------
// block = (b, 128-group chunk); 4 independent waves of 32 groups; NO LDS/barriers.
__global__ __launch_bounds__(256) void kM(
    const unsigned short* __restrict__ xbf, const unsigned short* __restrict__ Wcbf,
    const float* __restrict__ w3t, float* __restrict__ gbuf)
{
    const int b = blockIdx.x, gc = blockIdx.y;
    const int wv = threadIdx.x >> 6, lane = threadIdx.x & 63;
    const int col = lane & 15, quad = lane >> 4;
    const int g0 = gc * 128 + wv * 32;

    // A-operand (W rows, 32 groups x 96 k) held in registers for the whole wave
    short8 a[2][3];
    #pragma unroll
    for (int mt = 0; mt < 2; ++mt)
        #pragma unroll
        for (int ks = 0; ks < 3; ++ks)
            a[mt][ks] = *(const short8*)(Wcbf + (size_t)(g0 + mt * 16 + col) * KP + ks * 32 + quad * 8);

    float p[2][4][4];   // conv3 partials [mt][r][o], accumulated over n-tiles
    #pragma unroll
    for (int mt = 0; mt < 2; ++mt)
        #pragma unroll
        for (int r = 0; r < 4; ++r)
            #pragma unroll
            for (int o = 0; o < 4; ++o) p[mt][r][o] = 0.f;

    const unsigned short* __restrict__ xr = xbf + (size_t)b * HWP * KP + col * KP + quad * 8;
    const float* __restrict__ wbase = w3t + ((size_t)(g0 + quad * 4) * HWP + col) * 4;

    #pragma unroll
    for (int nt = 0; nt < 13; ++nt) {
        const short8 b0 = *(const short8*)(xr + nt * 16 * KP);
        const short8 b1v = *(const short8*)(xr + nt * 16 * KP + 32);
        const short8 b2v = *(const short8*)(xr + nt * 16 * KP + 64);
        floatx4 acc0 = {0.f, 0.f, 0.f, 0.f}, acc1 = {0.f, 0.f, 0.f, 0.f};
        acc0 = __builtin_amdgcn_mfma_f32_16x16x32_bf16(a[0][0], b0,  acc0, 0, 0, 0);
        acc0 = __builtin_amdgcn_mfma_f32_16x16x32_bf16(a[0][1], b1v, acc0, 0, 0, 0);
        acc0 = __builtin_amdgcn_mfma_f32_16x16x32_bf16(a[0][2], b2v, acc0, 0, 0, 0);
        acc1 = __builtin_amdgcn_mfma_f32_16x16x32_bf16(a[1][0], b0,  acc1, 0, 0, 0);
        acc1 = __builtin_amdgcn_mfma_f32_16x16x32_bf16(a[1][1], b1v, acc1, 0, 0, 0);
        acc1 = __builtin_amdgcn_mfma_f32_16x16x32_bf16(a[1][2], b2v, acc1, 0, 0, 0);
        // conv3 partial: C/D layout col(hw)=lane&15, row(g)=quad*4+r [m89]
        #pragma unroll
        for (int mt = 0; mt < 2; ++mt) {
            const floatx4 av = mt ? acc1 : acc0;
            #pragma unroll
            for (int r = 0; r < 4; ++r) {
                const floatx4 wv3 = *(const floatx4*)(wbase + ((size_t)(mt * 16 + r) * HWP + nt * 16) * 4);
                p[mt][r][0] = fmaf(av[r], wv3[0], p[mt][r][0]);
                p[mt][r][1] = fmaf(av[r], wv3[1], p[mt][r][1]);
                p[mt][r][2] = fmaf(av[r], wv3[2], p[mt][r][2]);
                p[mt][r][3] = fmaf(av[r], wv3[3], p[mt][r][3]);
            }
        }
    }

    // reduce over the 16 hw-lanes, relu, store float4 per group
    #pragma unroll
    for (int mt = 0; mt < 2; ++mt)
        #pragma unroll
        for (int r = 0; r < 4; ++r) {
            float q0 = p[mt][r][0], q1 = p[mt][r][1], q2 = p[mt][r][2], q3 = p[mt][r][3];
            #pragma unroll
            for (int s = 8; s >= 1; s >>= 1) {
                q0 += __shfl_down(q0, s, 16);
                q1 += __shfl_down(q1, s, 16);
                q2 += __shfl_down(q2, s, 16);
                q3 += __shfl_down(q3, s, 16);
            }
            if (col == 0) {
                const int g = g0 + mt * 16 + quad * 4 + r;
                floatx4 ov = {fmaxf(q0, 0.f), fmaxf(q1, 0.f), fmaxf(q2, 0.f), fmaxf(q3, 0.f)};
                *(floatx4*)(gbuf + ((size_t)b * 512 + g) * 4) = ov;
            }
        }
}

// ---- kF: out[b][l] += gbuf[b] . fct[:,l]  (out pre-set to fc_b) -------------
__global__ __launch_bounds__(256) void kF(
    const float* __restrict__ gbuf, const float* __restrict__ fct,
    float* __restrict__ out)
{
    const int b = blockIdx.x, t = threadIdx.x;
    if (t >= 240) return;
    const int l = t % 80, kp = t / 80;               // 3 k-parts
    const int k0 = kp * 683, k1 = (k0 + 683 < 2048) ? k0 + 683 : 2048;
    const float* __restrict__ gr = gbuf + (size_t)b * 2048;
    float s = 0.f;
    #pragma unroll 8
    for (int k = k0; k < k1; ++k) s = fmaf(gr[k], fct[k * 80 + l], s);
    atomicAdd(out + b * CIN + l, s);
}

extern "C" void kernel_launch(void* const* d_in, const int* in_sizes, int n_in,
                              void* d_out, int out_size, void* d_ws, size_t ws_size,
                              hipStream_t stream) {
    const float* x    = (const float*)d_in[0];
    const float* w1   = (const float*)d_in[1];
    const float* b1   = (const float*)d_in[2];
    const float* w2   = (const float*)d_in[3];
    const float* b2   = (const float*)d_in[4];
    const float* w3   = (const float*)d_in[5];
    const float* fc_w = (const float*)d_in[6];
    const float* fc_b = (const float*)d_in[7];
    float* out = (float*)d_out;

    const int B = in_sizes[0] / (CIN * NSP);   // 256

    // workspace: xbf | Wcf | Wcbf | w3t | fct | gbuf  (~15 MB)
    char* ws = (char*)d_ws;
    unsigned short* xbf = (unsigned short*)ws;                 // B*208*96*2
    size_t off = (size_t)B * HWP * KP * 2;
    float* Wcf   = (float*)(ws + off);  off += 512 * CIN * 4;  // f32 partials
    unsigned short* Wcbf = (unsigned short*)(ws + off); off += 512 * KP * 2;
    float* w3t   = (float*)(ws + off);  off += (size_t)512 * HWP * 4 * 4;
    float* fct   = (float*)(ws + off);  off += (size_t)2048 * 80 * 4;
    float* gbuf  = (float*)(ws + off);                          // B*2048*4

    hipMemsetAsync(Wcf, 0, 512 * CIN * 4, stream);
    const int nb_xp = B * 4;
    kPre<<<NB_WC + nb_xp + NB_W3 + NB_FT, 320, 0, stream>>>(
        x, w1, w2, w3, fc_w, Wcf, xbf, w3t, fct, nb_xp);
    kP2<<<512, 128, 0, stream>>>(w2, b1, b2, fc_b, Wcf, Wcbf, out, out_size);
    kM<<<dim3(B, 4), 256, 0, stream>>>(xbf, Wcbf, w3t, gbuf);
    kF<<<B, 256, 0, stream>>>(gbuf, fct, out);
}